// Round 4
// baseline (288.714 us; speedup 1.0000x reference)
//
#include <hip/hip_runtime.h>

static constexpr int B_   = 8;
static constexpr int C_   = 256;
static constexpr int CQK_ = 32;
static constexpr int N_   = 4096;   // 64*64

typedef __attribute__((ext_vector_type(4))) float f32x4;
typedef __attribute__((ext_vector_type(8))) short short8;
typedef __attribute__((ext_vector_type(2))) unsigned int u32x2;
typedef unsigned short ushort_t;

// round-to-nearest-even fp32 -> bf16
__device__ inline unsigned short f2bf(float f) {
    unsigned u = __float_as_uint(f);
    return (unsigned short)((u + 0x7FFFu + ((u >> 16) & 1u)) >> 16);
}
__device__ inline unsigned packbf(float lo, float hi) {
    return (unsigned)f2bf(lo) | ((unsigned)f2bf(hi) << 16);
}

// row-dependent XOR swizzle (16B granules) for the proj x-tile; involution
__device__ inline int swzbits(int m) {
    return ((m & 3) << 5) | (((m >> 3) & 1) << 4);
}

template <int OFF>
__device__ inline u32x2 tr8(unsigned a) {
    u32x2 d;
    asm volatile("ds_read_b64_tr_b16 %0, %1 offset:%2"
                 : "=v"(d) : "v"(a), "i"(OFF));
    return d;
}

__device__ inline short8 mk8(u32x2 lo, u32x2 hi) {
    union { unsigned u[4]; short8 s; } v;
    v.u[0] = lo.x; v.u[1] = lo.y; v.u[2] = hi.x; v.u[3] = hi.y;
    return v.s;
}

// ---------------------------------------------------------------------------
// prep: concat + convert weights to bf16, biases to f32 array
// ---------------------------------------------------------------------------
__global__ __launch_bounds__(256) void prep_kernel(
    const float* __restrict__ Wq, const float* __restrict__ bq,
    const float* __restrict__ Wk, const float* __restrict__ bk,
    const float* __restrict__ Wv, const float* __restrict__ bv,
    ushort_t* __restrict__ Wall, float* __restrict__ ball)
{
    const int r = blockIdx.x;
    const int t = threadIdx.x;
    const float* src;
    float bsrc;
    if (r < 32)      { src = Wq + (size_t)r * C_;        bsrc = bq[r]; }
    else if (r < 64) { src = Wk + (size_t)(r - 32) * C_; bsrc = bk[r - 32]; }
    else             { src = Wv + (size_t)(r - 64) * C_; bsrc = bv[r - 64]; }
    Wall[(size_t)r * C_ + t] = f2bf(src[t]);
    if (t == 0) ball[r] = bsrc;
}

// ---------------------------------------------------------------------------
// Projection via MFMA. Wave w owns oc-tiles tt = 4*tm + w (tm=0..4).
//  tm==0 (Q/K): C[oc][n] = mfma(W-frag, x-frag)  -> Qb/Kb row-major [n][ck]
//  tm>=1 (V):   C[n][oc] = mfma(x-frag, W-frag)  -> Vt[c][m] (transposed!)
// grid = 512 blocks (b = blk&7, XCD-affine), 256 threads (4 waves)
// ---------------------------------------------------------------------------
__global__ __launch_bounds__(256) void proj_kernel(
    const float* __restrict__ x,
    const ushort_t* __restrict__ Wall, const float* __restrict__ ball,
    ushort_t* __restrict__ Qb, ushort_t* __restrict__ Kb, ushort_t* __restrict__ Vt)
{
    __shared__ __align__(16) unsigned char xs[C_ * 128];   // 32 KB: [c][64n] bf16
    typedef __attribute__((address_space(3))) unsigned char lds_byte;
    const unsigned sbase = (unsigned)(size_t)(lds_byte*)xs;

    const int b  = blockIdx.x & 7;
    const int n0 = (blockIdx.x >> 3) << 6;
    const int t  = threadIdx.x;

    // ---- stage x[b, c, n0..n0+63] -> xs[c][n] bf16 (swizzled rows) ----
    {
        const int cst = t >> 4;
        const int n4  = (t & 15) << 2;
        const float* xb = x + (size_t)b * C_ * N_ + n0;
        #pragma unroll
        for (int i = 0; i < 16; ++i) {
            const int c = 16 * i + cst;
            float4 v = *(const float4*)(xb + (size_t)c * N_ + n4);
            u32x2 pk;
            pk.x = packbf(v.x, v.y);
            pk.y = packbf(v.z, v.w);
            *(u32x2*)(xs + c * 128 + ((n4 * 2) ^ swzbits(c))) = pk;
        }
    }
    __syncthreads();

    const int l  = t & 63, w = t >> 6;
    const int li = l & 15, g = l >> 4;
    const int rr = li >> 2, ss = l & 3;
    const int swz_tr = (rr << 5) | ((g & 1) << 4);

    f32x4 acc[5][4];
    #pragma unroll
    for (int i = 0; i < 5; ++i)
        #pragma unroll
        for (int j = 0; j < 4; ++j) acc[i][j] = (f32x4){0.f, 0.f, 0.f, 0.f};

    #pragma unroll 2
    for (int kg = 0; kg < 8; ++kg) {
        // x-frags: lane li holds 8 c-contiguous at item n=li+16jn (tr-reads)
        u32x2 pb[4][2];
        #pragma unroll
        for (int jn = 0; jn < 4; ++jn) {
            unsigned a = sbase + (32 * kg + 8 * g + rr) * 128
                       + ((32 * jn + 8 * ss) ^ swz_tr);
            pb[jn][0] = tr8<0>(a);
            pb[jn][1] = tr8<512>(a);
        }
        // W-frags: lane li holds 8 c-contiguous of row oc=16*(4tm+w)+li
        short8 af[5];
        #pragma unroll
        for (int tm = 0; tm < 5; ++tm)
            af[tm] = *(const short8*)(Wall + (size_t)(16 * (4 * tm + w) + li) * C_
                                      + 32 * kg + 8 * g);
        asm volatile("s_waitcnt lgkmcnt(0)" ::: "memory");
        __builtin_amdgcn_sched_barrier(0);
        #pragma unroll
        for (int jn = 0; jn < 4; ++jn) {
            short8 Bf = mk8(pb[jn][0], pb[jn][1]);
            acc[0][jn] = __builtin_amdgcn_mfma_f32_16x16x32_bf16(
                             af[0], Bf, acc[0][jn], 0, 0, 0);
            #pragma unroll
            for (int tm = 1; tm < 5; ++tm)
                acc[tm][jn] = __builtin_amdgcn_mfma_f32_16x16x32_bf16(
                                  Bf, af[tm], acc[tm][jn], 0, 0, 0);
        }
    }

    // ---- epilogue ----
    // tm=0: lane holds (oc = 16w+4g+r, n = n0+16jn+li) -> Q (w<2) or K (w>=2)
    {
        const int oc0 = 16 * w + 4 * g;
        float4 bias = *(const float4*)(ball + oc0);
        ushort_t* dst = (w < 2) ? Qb : Kb;
        const int col = (w < 2) ? oc0 : (oc0 - 32);
        #pragma unroll
        for (int jn = 0; jn < 4; ++jn) {
            const int n = n0 + 16 * jn + li;
            f32x4 a = acc[0][jn];
            u32x2 pk;
            pk.x = packbf(a[0] + bias.x, a[1] + bias.y);
            pk.y = packbf(a[2] + bias.z, a[3] + bias.w);
            *(u32x2*)(dst + (size_t)(b * N_ + n) * CQK_ + col) = pk;
        }
    }
    // tm>=1: lane holds (n = n0+16jn+4g+r, c = 16*(4tm+w)+li-64) -> Vt[c][m=n]
    #pragma unroll
    for (int tm = 1; tm < 5; ++tm) {
        const int c  = 16 * (4 * tm + w) + li - 64;
        const float bc = ball[64 + c];
        #pragma unroll
        for (int jn = 0; jn < 4; ++jn) {
            f32x4 a = acc[tm][jn];
            u32x2 pk;
            pk.x = packbf(a[0] + bc, a[1] + bc);
            pk.y = packbf(a[2] + bc, a[3] + bc);
            *(u32x2*)(Vt + (size_t)(b * C_ + c) * N_ + n0 + 16 * jn + 4 * g) = pk;
        }
    }
}

// ---------------------------------------------------------------------------
// Fused attention, barrier-free. Wave = 32 q x 128 c. Swapped QK -> S^T;
// P packed to wave-private LDS [32q][64m] (stride 144, bit4-XOR swizzle);
// PV: A = P via ds_read_b128, B = Vt via direct global 16B loads (L2).
// grid = 512 (b = blk&7 XCD-affine), 256 threads (4 waves)
// ---------------------------------------------------------------------------
__global__ __launch_bounds__(256) void attn_kernel(
    const float* __restrict__ x,
    const ushort_t* __restrict__ Qb, const ushort_t* __restrict__ Kb,
    const ushort_t* __restrict__ Vt,
    const float* __restrict__ gamma, float* __restrict__ out)
{
    __shared__ __align__(16) unsigned char Pl[4 * 32 * 144];   // 18432 B

    const int b  = blockIdx.x & 7;
    const int n0 = (blockIdx.x >> 3) << 6;
    const int t  = threadIdx.x;
    const int l  = t & 63, w = t >> 6;
    const int li = l & 15, g = l >> 4;
    const int hq = w & 1,  hc = w >> 1;
    unsigned char* Pw = Pl + w * 4608;
    const int xorq = (li & 1) << 4;

    // Q fragments (B-role: col=li -> q = n0+32hq+16jq+li)
    short8 qf[2];
    #pragma unroll
    for (int jq = 0; jq < 2; ++jq)
        qf[jq] = *(const short8*)(Qb + (size_t)(b * N_ + n0 + 32 * hq + 16 * jq + li) * CQK_ + 8 * g);

    f32x4 acc[2][8];
    #pragma unroll
    for (int i = 0; i < 2; ++i)
        #pragma unroll
        for (int j = 0; j < 8; ++j) acc[i][j] = (f32x4){0.f, 0.f, 0.f, 0.f};
    float rs[2] = {0.f, 0.f};

    const ushort_t* Kbb = Kb + (size_t)(b * N_) * CQK_;
    const ushort_t* Vtb = Vt + (size_t)b * C_ * N_;
    const f32x4 zf = {0.f, 0.f, 0.f, 0.f};

    for (int m0 = 0; m0 < N_; m0 += 64) {
        // K fragments (A-role: row=li -> m = m0+16jm+li)
        short8 kf[4];
        #pragma unroll
        for (int jm = 0; jm < 4; ++jm)
            kf[jm] = *(const short8*)(Kbb + (size_t)(m0 + 16 * jm + li) * CQK_ + 8 * g);
        // V fragments kb=0 (B-role: col=li -> c; k = m contiguous 8)
        short8 v0[8];
        #pragma unroll
        for (int jc = 0; jc < 8; ++jc)
            v0[jc] = *(const short8*)(Vtb + (size_t)(128 * hc + 16 * jc + li) * N_
                                      + m0 + 8 * g);

        // ---- S^T = K Q, exp, pack into private P ----
        #pragma unroll
        for (int jm = 0; jm < 4; ++jm) {
            #pragma unroll
            for (int jq = 0; jq < 2; ++jq) {
                f32x4 s = __builtin_amdgcn_mfma_f32_16x16x32_bf16(kf[jm], qf[jq], zf, 0, 0, 0);
                float p0 = __expf(s[0]), p1 = __expf(s[1]);
                float p2 = __expf(s[2]), p3 = __expf(s[3]);
                rs[jq] += p0 + p1 + p2 + p3;
                u32x2 pk; pk.x = packbf(p0, p1); pk.y = packbf(p2, p3);
                *(u32x2*)(Pw + (16 * jq + li) * 144
                             + ((32 * jm + 8 * g) ^ xorq)) = pk;
            }
        }
        asm volatile("s_waitcnt lgkmcnt(0)" ::: "memory");
        __builtin_amdgcn_sched_barrier(0);

        // V fragments kb=1 (issued here; overlap kb=0 MFMAs)
        short8 v1[8];
        #pragma unroll
        for (int jc = 0; jc < 8; ++jc)
            v1[jc] = *(const short8*)(Vtb + (size_t)(128 * hc + 16 * jc + li) * N_
                                      + m0 + 32 + 8 * g);

        // ---- PV kb=0 ----
        {
            short8 pa[2];
            #pragma unroll
            for (int jq = 0; jq < 2; ++jq)
                pa[jq] = *(const short8*)(Pw + (16 * jq + li) * 144
                                             + ((16 * g) ^ xorq));
            #pragma unroll
            for (int jq = 0; jq < 2; ++jq)
                #pragma unroll
                for (int jc = 0; jc < 8; ++jc)
                    acc[jq][jc] = __builtin_amdgcn_mfma_f32_16x16x32_bf16(
                                      pa[jq], v0[jc], acc[jq][jc], 0, 0, 0);
        }
        // ---- PV kb=1 ----
        {
            short8 pa[2];
            #pragma unroll
            for (int jq = 0; jq < 2; ++jq)
                pa[jq] = *(const short8*)(Pw + (16 * jq + li) * 144
                                             + ((64 + 16 * g) ^ xorq));
            #pragma unroll
            for (int jq = 0; jq < 2; ++jq)
                #pragma unroll
                for (int jc = 0; jc < 8; ++jc)
                    acc[jq][jc] = __builtin_amdgcn_mfma_f32_16x16x32_bf16(
                                      pa[jq], v1[jc], acc[jq][jc], 0, 0, 0);
        }
    }

    // ---- softmax denominator: reduce over g-groups, redistribute ----
    #pragma unroll
    for (int jq = 0; jq < 2; ++jq) {
        rs[jq] += __shfl_xor(rs[jq], 16, 64);
        rs[jq] += __shfl_xor(rs[jq], 32, 64);
    }
    // lane (li,g) now holds rowsum of q = ..+li; epilogue needs q-row = 4g+r
    float inv[2][4];
    #pragma unroll
    for (int jq = 0; jq < 2; ++jq)
        #pragma unroll
        for (int r = 0; r < 4; ++r) {
            int v = __builtin_amdgcn_ds_bpermute((4 * g + r) * 4,
                                                 __float_as_int(rs[jq]));
            inv[jq][r] = 1.0f / __int_as_float(v);
        }

    const float gm = gamma[0];
    #pragma unroll
    for (int jq = 0; jq < 2; ++jq)
        #pragma unroll
        for (int jc = 0; jc < 8; ++jc) {
            const int c = 128 * hc + 16 * jc + li;
            const size_t rowoff = (size_t)(b * C_ + c) * N_
                                + n0 + 32 * hq + 16 * jq + 4 * g;
            float4 xv = *(const float4*)(x + rowoff);
            f32x4 a = acc[jq][jc];
            float4 o;
            o.x = gm * a[0] * inv[jq][0] + xv.x;
            o.y = gm * a[1] * inv[jq][1] + xv.y;
            o.z = gm * a[2] * inv[jq][2] + xv.z;
            o.w = gm * a[3] * inv[jq][3] + xv.w;
            *(float4*)(out + rowoff) = o;
        }
}

// ---------------------------------------------------------------------------
extern "C" void kernel_launch(void* const* d_in, const int* in_sizes, int n_in,
                              void* d_out, int out_size, void* d_ws, size_t ws_size,
                              hipStream_t stream)
{
    const float* x     = (const float*)d_in[0];
    const float* Wq    = (const float*)d_in[1];
    const float* bq    = (const float*)d_in[2];
    const float* Wk    = (const float*)d_in[3];
    const float* bk    = (const float*)d_in[4];
    const float* Wv    = (const float*)d_in[5];
    const float* bv    = (const float*)d_in[6];
    const float* gamma = (const float*)d_in[7];
    float* out = (float*)d_out;

    ushort_t* ws = (ushort_t*)d_ws;
    ushort_t* Qb   = ws;                                  // B*N*32 bf16
    ushort_t* Kb   = Qb + (size_t)B_ * N_ * CQK_;         // B*N*32 bf16
    ushort_t* Vt   = Kb + (size_t)B_ * N_ * CQK_;         // B*C*N bf16 (V^T!)
    ushort_t* Wall = Vt + (size_t)B_ * C_ * N_;           // 320*256 bf16
    float*    ball = (float*)(Wall + (size_t)320 * C_);   // 320 f32

    prep_kernel<<<320, 256, 0, stream>>>(Wq, bq, Wk, bk, Wv, bv, Wall, ball);
    proj_kernel<<<B_ * (N_ / 64), 256, 0, stream>>>(x, Wall, ball, Qb, Kb, Vt);
    attn_kernel<<<B_ * (N_ / 64), 256, 0, stream>>>(x, Qb, Kb, Vt, gamma, out);
}

// Round 5
// 159.228 us; speedup vs baseline: 1.8132x; 1.8132x over previous
//
#include <hip/hip_runtime.h>

static constexpr int B_   = 8;
static constexpr int C_   = 256;
static constexpr int CQK_ = 32;
static constexpr int N_   = 4096;   // 64*64

typedef __attribute__((ext_vector_type(4))) float f32x4;
typedef __attribute__((ext_vector_type(8))) short short8;
typedef __attribute__((ext_vector_type(2))) unsigned int u32x2;
typedef unsigned short ushort_t;

// round-to-nearest-even fp32 -> bf16
__device__ inline unsigned short f2bf(float f) {
    unsigned u = __float_as_uint(f);
    return (unsigned short)((u + 0x7FFFu + ((u >> 16) & 1u)) >> 16);
}
__device__ inline unsigned packbf(float lo, float hi) {
    return (unsigned)f2bf(lo) | ((unsigned)f2bf(hi) << 16);
}

// row-dependent XOR swizzle (16B granules) for the proj x-tile; involution
__device__ inline int swzbits(int m) {
    return ((m & 3) << 5) | (((m >> 3) & 1) << 4);
}

template <int OFF>
__device__ inline u32x2 tr8(unsigned a) {
    u32x2 d;
    asm volatile("ds_read_b64_tr_b16 %0, %1 offset:%2"
                 : "=v"(d) : "v"(a), "i"(OFF));
    return d;
}

__device__ inline short8 mk8(u32x2 lo, u32x2 hi) {
    union { unsigned u[4]; short8 s; } v;
    v.u[0] = lo.x; v.u[1] = lo.y; v.u[2] = hi.x; v.u[3] = hi.y;
    return v.s;
}

// ---------------------------------------------------------------------------
// prep: concat + convert weights to bf16, biases to f32 array
// ---------------------------------------------------------------------------
__global__ __launch_bounds__(256) void prep_kernel(
    const float* __restrict__ Wq, const float* __restrict__ bq,
    const float* __restrict__ Wk, const float* __restrict__ bk,
    const float* __restrict__ Wv, const float* __restrict__ bv,
    ushort_t* __restrict__ Wall, float* __restrict__ ball)
{
    const int r = blockIdx.x;
    const int t = threadIdx.x;
    const float* src;
    float bsrc;
    if (r < 32)      { src = Wq + (size_t)r * C_;        bsrc = bq[r]; }
    else if (r < 64) { src = Wk + (size_t)(r - 32) * C_; bsrc = bk[r - 32]; }
    else             { src = Wv + (size_t)(r - 64) * C_; bsrc = bv[r - 64]; }
    Wall[(size_t)r * C_ + t] = f2bf(src[t]);
    if (t == 0) ball[r] = bsrc;
}

// ---------------------------------------------------------------------------
// Projection via MFMA. Wave w owns oc-tiles tt = 4*tm + w (tm=0..4).
//  tm==0 (Q/K): C[oc][n] = mfma(W-frag, x-frag)  -> Qb/Kb row-major [n][ck]
//  tm>=1 (V):   C[n][oc] = mfma(x-frag, W-frag)  -> Vt chunked+swizzled:
//    byte addr = ((b*64 + m/64)*256 + c)*128 + ((2*(m&63)) ^ ((c&7)<<4))
//    (this is the exact LDS image attn DMA-stages per 64-m chunk)
// grid = 512 blocks (b = blk&7, XCD-affine), 256 threads (4 waves)
// ---------------------------------------------------------------------------
__global__ __launch_bounds__(256) void proj_kernel(
    const float* __restrict__ x,
    const ushort_t* __restrict__ Wall, const float* __restrict__ ball,
    ushort_t* __restrict__ Qb, ushort_t* __restrict__ Kb, ushort_t* __restrict__ Vt)
{
    __shared__ __align__(16) unsigned char xs[C_ * 128];   // 32 KB: [c][64n] bf16
    typedef __attribute__((address_space(3))) unsigned char lds_byte;
    const unsigned sbase = (unsigned)(size_t)(lds_byte*)xs;

    const int b  = blockIdx.x & 7;
    const int n0 = (blockIdx.x >> 3) << 6;
    const int t  = threadIdx.x;

    // ---- stage x[b, c, n0..n0+63] -> xs[c][n] bf16 (swizzled rows) ----
    {
        const int cst = t >> 4;
        const int n4  = (t & 15) << 2;
        const float* xb = x + (size_t)b * C_ * N_ + n0;
        #pragma unroll
        for (int i = 0; i < 16; ++i) {
            const int c = 16 * i + cst;
            float4 v = *(const float4*)(xb + (size_t)c * N_ + n4);
            u32x2 pk;
            pk.x = packbf(v.x, v.y);
            pk.y = packbf(v.z, v.w);
            *(u32x2*)(xs + c * 128 + ((n4 * 2) ^ swzbits(c))) = pk;
        }
    }
    __syncthreads();

    const int l  = t & 63, w = t >> 6;
    const int li = l & 15, g = l >> 4;
    const int rr = li >> 2, ss = l & 3;
    const int swz_tr = (rr << 5) | ((g & 1) << 4);

    f32x4 acc[5][4];
    #pragma unroll
    for (int i = 0; i < 5; ++i)
        #pragma unroll
        for (int j = 0; j < 4; ++j) acc[i][j] = (f32x4){0.f, 0.f, 0.f, 0.f};

    #pragma unroll 2
    for (int kg = 0; kg < 8; ++kg) {
        u32x2 pb[4][2];
        #pragma unroll
        for (int jn = 0; jn < 4; ++jn) {
            unsigned a = sbase + (32 * kg + 8 * g + rr) * 128
                       + ((32 * jn + 8 * ss) ^ swz_tr);
            pb[jn][0] = tr8<0>(a);
            pb[jn][1] = tr8<512>(a);
        }
        short8 af[5];
        #pragma unroll
        for (int tm = 0; tm < 5; ++tm)
            af[tm] = *(const short8*)(Wall + (size_t)(16 * (4 * tm + w) + li) * C_
                                      + 32 * kg + 8 * g);
        asm volatile("s_waitcnt lgkmcnt(0)" ::: "memory");
        __builtin_amdgcn_sched_barrier(0);
        #pragma unroll
        for (int jn = 0; jn < 4; ++jn) {
            short8 Bf = mk8(pb[jn][0], pb[jn][1]);
            acc[0][jn] = __builtin_amdgcn_mfma_f32_16x16x32_bf16(
                             af[0], Bf, acc[0][jn], 0, 0, 0);
            #pragma unroll
            for (int tm = 1; tm < 5; ++tm)
                acc[tm][jn] = __builtin_amdgcn_mfma_f32_16x16x32_bf16(
                                  Bf, af[tm], acc[tm][jn], 0, 0, 0);
        }
    }

    // ---- epilogue ----
    // tm=0: lane holds (oc = 16w+4g+r, n = n0+16jn+li) -> Q (w<2) or K (w>=2)
    {
        const int oc0 = 16 * w + 4 * g;
        float4 bias = *(const float4*)(ball + oc0);
        ushort_t* dst = (w < 2) ? Qb : Kb;
        const int col = (w < 2) ? oc0 : (oc0 - 32);
        #pragma unroll
        for (int jn = 0; jn < 4; ++jn) {
            const int n = n0 + 16 * jn + li;
            f32x4 a = acc[0][jn];
            u32x2 pk;
            pk.x = packbf(a[0] + bias.x, a[1] + bias.y);
            pk.y = packbf(a[2] + bias.z, a[3] + bias.w);
            *(u32x2*)(dst + (size_t)(b * N_ + n) * CQK_ + col) = pk;
        }
    }
    // tm>=1: lane holds (m' = 16jn+4g+r within chunk, c) -> swizzled Vt chunk
    {
        const int sx = (li & 7) << 4;
        #pragma unroll
        for (int tm = 1; tm < 5; ++tm) {
            const int c  = 16 * (4 * tm + w) + li - 64;
            const float bc = ball[64 + c];
            char* vrow = (char*)Vt
                       + ((size_t)(b * 64 + (n0 >> 6)) * 256 + c) * 128;
            #pragma unroll
            for (int jn = 0; jn < 4; ++jn) {
                f32x4 a = acc[tm][jn];
                u32x2 pk;
                pk.x = packbf(a[0] + bc, a[1] + bc);
                pk.y = packbf(a[2] + bc, a[3] + bc);
                *(u32x2*)(vrow + ((32 * jn + 8 * g) ^ sx)) = pk;
            }
        }
    }
}

// ---------------------------------------------------------------------------
// Fused attention: double-buffered V chunks via global_load_lds DMA,
// K reg-prefetch, wave-private P in LDS, one barrier per chunk.
// grid = 512 (b = blk&7 XCD-affine), 256 threads (4 waves: 32q x 128c each)
// LDS: buf0 32KB | buf1 32KB | P 4x4KB  = 80 KiB -> 2 blocks/CU
// ---------------------------------------------------------------------------
__global__ __launch_bounds__(256) void attn_kernel(
    const float* __restrict__ x,
    const ushort_t* __restrict__ Qb, const ushort_t* __restrict__ Kb,
    const ushort_t* __restrict__ Vt,
    const float* __restrict__ gamma, float* __restrict__ out)
{
    __shared__ __align__(16) unsigned char smem[81920];

    const int b  = blockIdx.x & 7;
    const int n0 = (blockIdx.x >> 3) << 6;
    const int t  = threadIdx.x;
    const int l  = t & 63, w = t >> 6;
    const int li = l & 15, g = l >> 4;
    const int hq = w & 1,  hc = w >> 1;
    const int sx = (li & 7) << 4;
    unsigned char* Pw = smem + 65536 + w * 4096;

    // Q fragments (B-role: col=li -> q = n0+32hq+16jq+li)
    short8 qf[2];
    #pragma unroll
    for (int jq = 0; jq < 2; ++jq)
        qf[jq] = *(const short8*)(Qb + (size_t)(b * N_ + n0 + 32 * hq + 16 * jq + li) * CQK_ + 8 * g);

    f32x4 acc[2][8];
    #pragma unroll
    for (int i = 0; i < 2; ++i)
        #pragma unroll
        for (int j = 0; j < 8; ++j) acc[i][j] = (f32x4){0.f, 0.f, 0.f, 0.f};
    float rs[2] = {0.f, 0.f};

    const ushort_t* Kbb = Kb + (size_t)(b * N_) * CQK_;
    const char* Vtb = (const char*)Vt + (size_t)b * 64 * 32768;
    const f32x4 zf = {0.f, 0.f, 0.f, 0.f};

    short8 kfA[4], kfB[4];

    // ---- prologue: DMA chunk 0 -> buf0, K chunk 0 -> kfA ----
    {
        const char* gsrc = Vtb + t * 16;
        #pragma unroll
        for (int i = 0; i < 8; ++i)
            __builtin_amdgcn_global_load_lds(
                (const __attribute__((address_space(1))) unsigned int*)(gsrc + i * 4096),
                (__attribute__((address_space(3))) unsigned int*)(smem + t * 16 + i * 4096),
                16, 0, 0);
        #pragma unroll
        for (int jm = 0; jm < 4; ++jm)
            kfA[jm] = *(const short8*)(Kbb + (size_t)(16 * jm + li) * CQK_ + 8 * g);
    }
    asm volatile("s_waitcnt vmcnt(0)" ::: "memory");
    __syncthreads();

#define CHUNK_BODY(MC, BUFR, BUFW, KFC, KFN)                                    \
    {                                                                           \
        const int mcn = ((MC) + 1) & 63;                                        \
        /* 1. DMA next V chunk (async, drained at end-of-body) */               \
        const char* gsrc = Vtb + (size_t)mcn * 32768 + t * 16;                  \
        _Pragma("unroll")                                                       \
        for (int i = 0; i < 8; ++i)                                             \
            __builtin_amdgcn_global_load_lds(                                   \
                (const __attribute__((address_space(1))) unsigned int*)(gsrc + i * 4096), \
                (__attribute__((address_space(3))) unsigned int*)((BUFW) + t * 16 + i * 4096), \
                16, 0, 0);                                                      \
        /* 2. prefetch next K fragments into regs */                            \
        _Pragma("unroll")                                                       \
        for (int jm = 0; jm < 4; ++jm)                                          \
            KFN[jm] = *(const short8*)(Kbb + (size_t)(64 * mcn + 16 * jm + li) * CQK_ + 8 * g); \
        /* 3. S^T = K Q, exp, pack into wave-private P */                       \
        _Pragma("unroll")                                                       \
        for (int jm = 0; jm < 4; ++jm) {                                        \
            _Pragma("unroll")                                                   \
            for (int jq = 0; jq < 2; ++jq) {                                    \
                f32x4 s = __builtin_amdgcn_mfma_f32_16x16x32_bf16(              \
                              KFC[jm], qf[jq], zf, 0, 0, 0);                    \
                float e0 = __expf(s[0]), e1 = __expf(s[1]);                     \
                float e2 = __expf(s[2]), e3 = __expf(s[3]);                     \
                rs[jq] += (e0 + e1) + (e2 + e3);                                \
                u32x2 pk; pk.x = packbf(e0, e1); pk.y = packbf(e2, e3);         \
                *(u32x2*)(Pw + (16 * jq + li) * 128                             \
                             + ((32 * jm + 8 * g) ^ sx)) = pk;                  \
            }                                                                   \
        }                                                                       \
        asm volatile("s_waitcnt lgkmcnt(0)" ::: "memory");                      \
        __builtin_amdgcn_sched_barrier(0);                                      \
        /* 4. PV: A = P (ds_read_b128), B = V chunk (ds_read_b128, swz) */      \
        _Pragma("unroll")                                                       \
        for (int kb = 0; kb < 2; ++kb) {                                        \
            short8 pa[2], vb[8];                                                \
            _Pragma("unroll")                                                   \
            for (int jq = 0; jq < 2; ++jq)                                      \
                pa[jq] = *(const short8*)(Pw + (16 * jq + li) * 128             \
                                             + ((64 * kb + 16 * g) ^ sx));      \
            _Pragma("unroll")                                                   \
            for (int jc = 0; jc < 8; ++jc)                                      \
                vb[jc] = *(const short8*)((BUFR)                                \
                             + (128 * hc + 16 * jc + li) * 128                  \
                             + ((64 * kb + 16 * g) ^ sx));                      \
            _Pragma("unroll")                                                   \
            for (int jq = 0; jq < 2; ++jq)                                      \
                _Pragma("unroll")                                               \
                for (int jc = 0; jc < 8; ++jc)                                  \
                    acc[jq][jc] = __builtin_amdgcn_mfma_f32_16x16x32_bf16(      \
                                      pa[jq], vb[jc], acc[jq][jc], 0, 0, 0);    \
        }                                                                       \
        /* 5. drain DMA/K-prefetch, one barrier per chunk */                    \
        asm volatile("s_waitcnt vmcnt(0)" ::: "memory");                        \
        __syncthreads();                                                        \
    }

    for (int mc = 0; mc < 64; mc += 2) {
        CHUNK_BODY(mc,     smem,         smem + 32768, kfA, kfB)
        CHUNK_BODY(mc + 1, smem + 32768, smem,         kfB, kfA)
    }
#undef CHUNK_BODY

    // ---- softmax denominator: reduce over g-groups, redistribute ----
    #pragma unroll
    for (int jq = 0; jq < 2; ++jq) {
        rs[jq] += __shfl_xor(rs[jq], 16, 64);
        rs[jq] += __shfl_xor(rs[jq], 32, 64);
    }
    float inv[2][4];
    #pragma unroll
    for (int jq = 0; jq < 2; ++jq)
        #pragma unroll
        for (int r = 0; r < 4; ++r) {
            int v = __builtin_amdgcn_ds_bpermute((4 * g + r) * 4,
                                                 __float_as_int(rs[jq]));
            inv[jq][r] = 1.0f / __int_as_float(v);
        }

    const float gm = gamma[0];
    #pragma unroll
    for (int jq = 0; jq < 2; ++jq)
        #pragma unroll
        for (int jc = 0; jc < 8; ++jc) {
            const int c = 128 * hc + 16 * jc + li;
            const size_t rowoff = (size_t)(b * C_ + c) * N_
                                + n0 + 32 * hq + 16 * jq + 4 * g;
            float4 xv = *(const float4*)(x + rowoff);
            f32x4 a = acc[jq][jc];
            float4 o;
            o.x = gm * a[0] * inv[jq][0] + xv.x;
            o.y = gm * a[1] * inv[jq][1] + xv.y;
            o.z = gm * a[2] * inv[jq][2] + xv.z;
            o.w = gm * a[3] * inv[jq][3] + xv.w;
            *(float4*)(out + rowoff) = o;
        }
}

// ---------------------------------------------------------------------------
extern "C" void kernel_launch(void* const* d_in, const int* in_sizes, int n_in,
                              void* d_out, int out_size, void* d_ws, size_t ws_size,
                              hipStream_t stream)
{
    const float* x     = (const float*)d_in[0];
    const float* Wq    = (const float*)d_in[1];
    const float* bq    = (const float*)d_in[2];
    const float* Wk    = (const float*)d_in[3];
    const float* bk    = (const float*)d_in[4];
    const float* Wv    = (const float*)d_in[5];
    const float* bv    = (const float*)d_in[6];
    const float* gamma = (const float*)d_in[7];
    float* out = (float*)d_out;

    ushort_t* ws = (ushort_t*)d_ws;
    ushort_t* Qb   = ws;                                  // B*N*32 bf16
    ushort_t* Kb   = Qb + (size_t)B_ * N_ * CQK_;         // B*N*32 bf16
    ushort_t* Vt   = Kb + (size_t)B_ * N_ * CQK_;         // B*64 chunks * 32KB
    ushort_t* Wall = Vt + (size_t)B_ * C_ * N_;           // 320*256 bf16
    float*    ball = (float*)(Wall + (size_t)320 * C_);   // 320 f32

    prep_kernel<<<320, 256, 0, stream>>>(Wq, bq, Wk, bk, Wv, bv, Wall, ball);
    proj_kernel<<<B_ * (N_ / 64), 256, 0, stream>>>(x, Wall, ball, Qb, Kb, Vt);
    attn_kernel<<<B_ * (N_ / 64), 256, 0, stream>>>(x, Qb, Kb, Vt, gamma, out);
}